// Round 7
// baseline (144.970 us; speedup 1.0000x reference)
//
#include <hip/hip_runtime.h>
#include <stdint.h>

#define NB 8
#define NPRED 25200
#define NTOP 1000
#define NCLS 80
#define CONF_T 0.25f
#define IOU_THR 0.45f
#define MAXWH 4096.0f
#define NKEYS 2048
#define NBINSF 4096   // fine bins: (bits>>12) - 0x3E800, clamped [0, 4095]
#define FSH 12
#define FBASE 0x3E800
#define SBLK 128
#define SBPB 197   // ceil(25200/128): 197*128 = 25216

typedef unsigned long long u64;

__device__ __forceinline__ u64 shfl_u64(u64 v, int src) {
    int lo = __shfl((int)(unsigned)v, src);
    int hi = __shfl((int)(unsigned)(v >> 32), src);
    return ((u64)(unsigned)hi << 32) | (unsigned)lo;
}

// ---------------------------------------------------------------------------
// K1: score/class per pred. 256 threads / 128 preds: thread pair (t>>1, t&1)
// splits the 80-class argmax 40/40, combined with one __shfl_xor.
// Staging via global_load_lds width=16 (no VGPR round trip).
// ---------------------------------------------------------------------------
__global__ __launch_bounds__(256) void k_score(const float* __restrict__ x,
                                               float* __restrict__ msc,
                                               int* __restrict__ cls) {
#pragma clang fp contract(off)
    __shared__ __align__(16) float sm[SBLK * 85];
    const int b = blockIdx.x / SBPB;
    const int blk = blockIdx.x % SBPB;
    const int t = threadIdx.x;
    const int wave = t >> 6, lane = t & 63;
    const long long TOT4 = (long long)NB * NPRED * 85 / 4;  // 4,284,000
    const long long base4 = ((long long)b * NPRED + (long long)blk * SBLK) * 85 / 4;
    const float4* x4 = (const float4*)x;
    const int tile4 = SBLK * 85 / 4;  // 2720

    for (int k = 0; k < 11; ++k) {
        int ib = k * 256 + wave * 64;      // wave-uniform lds base (float4 units)
        int fi = ib + lane;
        if (fi < tile4) {
            long long gi = base4 + fi;
            if (gi >= TOT4) gi = TOT4 - 1;  // tail clamp (outputs guarded below)
            __builtin_amdgcn_global_load_lds(
                (const __attribute__((address_space(1))) void*)(x4 + gi),
                (__attribute__((address_space(3))) void*)(sm + (size_t)ib * 4),
                16, 0, 0);
        }
    }
    __syncthreads();

    const int p = t >> 1;        // pred within block [0,128)
    const int h = t & 1;         // class-half: 0 -> classes 0..39, 1 -> 40..79
    const int pred = blk * SBLK + p;
    const float* rowp = &sm[p * 85];
    float obj = rowp[4];
    const int cb = 5 + h * 40;
    float best = rowp[cb];
    int bid = h * 40;
    for (int c = 1; c < 40; ++c) {
        float v = rowp[cb + c];
        if (v > best) { best = v; bid = h * 40 + c; }  // strict >: first occurrence
    }
    float obest = __shfl_xor(best, 1);
    int obid = __shfl_xor(bid, 1);
    if (h == 0 && pred < NPRED) {
        float fb = best; int fc = bid;
        if (obest > fb) { fb = obest; fc = obid; }  // ties -> lower class idx (h=0)
        float score = obj * fb;
        int q = b * NPRED + pred;
        msc[q] = (score > CONF_T) ? score : -1.0f;
        cls[q] = fc;
    }
}

// ---------------------------------------------------------------------------
// K2 (fused tail), round 7: THE SORT IS GONE. With 4096 fine score bins,
// a suffix-scan of the histogram gives each bin its exact base offset in
// rank order; candidates scatter directly to keys[base + atomicAdd] (bin-
// sorted in ONE pass), and a per-bin-run insertion sort (runs ~1.4 elems,
// disjoint segments, full (~bits,idx) key) makes the order exact -- incl.
// clamped-bin edge cases and score-bit ties (stable: idx ascending).
// Replaces round 5/6's bitonic (~45-51 levels, 90-200 shfls, 20-30 barriers
// per thread) with ~60 scan ops + 1 scatter + tiny cleanup; ~13 barriers
// total. Run-head detection reads only the neighbor key's BIN (hi dword >>
// 12), which is invariant under concurrent intra-segment permutation and
// tear-safe (per-dword LDS writes) -> no extra sync needed.
// Rank/greedy tail (bm bitmasks + one-wave-per-class ballot loop) kept from
// round 6. Exactness of class-local NMS unchanged (cross-class IoU exactly
// 0; same-class IoU identical expression; absmax 0.0 for 7 rounds).
// Slots >= 2048 are dropped: requires >1024 candidates in ONE fine bin
// (same 20 leading score bits) -- same impossibility tier as prior rounds'
// CAP=2048 compaction drop.
// ---------------------------------------------------------------------------
__global__ __launch_bounds__(1024) void k_fused(const float* __restrict__ x,
                                                const float* __restrict__ msc,
                                                const int* __restrict__ cls,
                                                float* __restrict__ out) {
#pragma clang fp contract(off)
    __shared__ __align__(16) unsigned char uni[NKEYS * 8];  // keys | bm+sup
    __shared__ __align__(16) unsigned hh[NBINSF];
    __shared__ unsigned wtot[16];
    __shared__ __align__(16) float4 obx[NTOP];   // un-offset xyxy
    __shared__ float oco[NTOP];                  // cls * 4096
    __shared__ float osc[NTOP];                  // score
    __shared__ int   ocl[NTOP];                  // class id, -1 if invalid
    __shared__ int ovf;
    u64* keys = (u64*)uni;
    const int b = blockIdx.x, t = threadIdx.x;
    const int wave = t >> 6, lane = t & 63;
    const float* ms = msc + (size_t)b * NPRED;

    // single global pass: stash msc in registers (25*1024 = 25600 >= 25200)
    float sv[25];
#pragma unroll
    for (int k = 0; k < 25; ++k) {
        int p = t + k * 1024;
        sv[k] = (p < NPRED) ? ms[p] : -1.0f;
    }

    ((uint4*)hh)[t] = make_uint4(0u, 0u, 0u, 0u);   // 1024 x 16B = 16 KB exact
    if (t == 0) ovf = 0;
    __syncthreads();

    // pass A: fine histogram of score bits (LDS atomics, from regs)
#pragma unroll
    for (int k = 0; k < 25; ++k) {
        float s = sv[k];
        if (s > CONF_T) {
            unsigned bits = __float_as_uint(s);
            int bin = (int)(bits >> FSH) - FBASE;
            bin = bin < 0 ? 0 : (bin > NBINSF - 1 ? NBINSF - 1 : bin);
            atomicAdd(&hh[bin], 1u);
        }
    }
    __syncthreads();

    // suffix-scan: hh[bin] <- count of candidates in bins STRICTLY ABOVE bin
    // (= exact base offset of bin's segment in descending-score rank order).
    uint4 hc = ((const uint4*)hh)[t];          // my 4 bins [4t, 4t+4)
    unsigned psum = hc.x + hc.y + hc.z + hc.w;
    unsigned v = psum;                          // in-wave inclusive suffix scan
    for (int d = 1; d < 64; d <<= 1) {
        unsigned o = __shfl_down(v, d);
        if (lane + d < 64) v += o;
    }
    if (lane == 0) wtot[wave] = v;              // wave totals
    // pad keys while waiting (independent of hh/wtot)
    keys[t] = ~0ULL; keys[t + 1024] = ~0ULL;
    __syncthreads();
    unsigned after = 0;
    for (int w2 = wave + 1; w2 < 16; ++w2) after += wtot[w2];  // broadcast reads
    unsigned exclSuf = after + (v - psum);      // strictly after my chunk
    unsigned o3 = exclSuf;                      // bin 4t+3 = highest score
    unsigned o2 = o3 + hc.w;
    unsigned o1 = o2 + hc.z;
    unsigned o0 = o1 + hc.y;
    ((uint4*)hh)[t] = make_uint4(o0, o1, o2, o3);
    __syncthreads();

    // pass B: scatter candidates to their rank segment (bin-sorted array)
#pragma unroll
    for (int k = 0; k < 25; ++k) {
        float s = sv[k];
        if (s > CONF_T) {
            unsigned bits = __float_as_uint(s);
            int bin = (int)(bits >> FSH) - FBASE;
            bin = bin < 0 ? 0 : (bin > NBINSF - 1 ? NBINSF - 1 : bin);
            unsigned slot = atomicAdd(&hh[bin], 1u);
            if (slot < (unsigned)NKEYS)
                keys[slot] = ((u64)(~bits) << 32) | (unsigned)(t + k * 1024);
        }
    }
    __syncthreads();

    // cleanup: insertion-sort each same-bin run (disjoint; ~1.4 elems avg)
    auto binOf = [](u64 kk) -> int {
        unsigned bits = ~(unsigned)(kk >> 32);
        int bin = (int)(bits >> FSH) - FBASE;
        return bin < 0 ? 0 : (bin > NBINSF - 1 ? NBINSF - 1 : bin);
    };
#pragma unroll
    for (int pp = 0; pp < 2; ++pp) {
        int p = t + pp * 1024;
        u64 k0 = keys[p];
        if (k0 == ~0ULL) continue;
        int mybin = binOf(k0);
        bool head = (p == 0) || (keys[p - 1] == ~0ULL) || (binOf(keys[p - 1]) != mybin);
        if (!head) continue;
        int e = p + 1;
        while (e < NKEYS) {
            u64 kn = keys[e];
            if (kn == ~0ULL || binOf(kn) != mybin) break;
            ++e;
        }
        for (int i2 = p + 1; i2 < e; ++i2) {    // tiny insertion sort
            u64 kv = keys[i2];
            int j2 = i2 - 1;
            while (j2 >= p && keys[j2] > kv) { keys[j2 + 1] = keys[j2]; --j2; }
            keys[j2 + 1] = kv;
        }
    }
    __syncthreads();

    // gather top-1000 into LDS SoA
    if (t < NTOP) {
        u64 key = keys[t];
        unsigned p = (unsigned)key;
        float score = __uint_as_float(~(unsigned)(key >> 32));
        bool vd = score > CONF_T;
        float4 o = make_float4(0.f, 0.f, 0.f, 0.f);
        float co = 0.f; int cid = -1;
        if (vd) {
            const float* xp = x + ((size_t)b * NPRED + p) * 85;
            float xc = xp[0], yc = xp[1], w = xp[2], h = xp[3];
            float hw = w * 0.5f, hh2 = h * 0.5f;
            o.x = xc - hw; o.y = yc - hh2; o.z = xc + hw; o.w = yc + hh2;
            cid = cls[(size_t)b * NPRED + p];
            co = (float)cid * MAXWH;
        }
        obx[t] = o; oco[t] = co; osc[t] = score; ocl[t] = cid;
    }
    __syncthreads();    // keys dead; overlay per-class rank bitmasks + sup

    u64* bm = (u64*)uni;                  // [80][16] u64 = 10240 B
    unsigned char* sup = uni + 10240;     // 1000 B
    for (int i = t; i < NCLS * 16; i += 1024) bm[i] = 0;
    if (t < NTOP) sup[t] = 0;
    __syncthreads();
    if (t < NTOP && ocl[t] >= 0)
        atomicOr(&bm[ocl[t] * 16 + (t >> 6)], 1ull << (t & 63));
    __syncthreads();

    // ---- per-class ballot greedy: one wave per class, lane = rank order ----
    {
        for (int c2 = wave; c2 < NCLS; c2 += 16) {
            u64 w = (lane < 16) ? bm[c2 * 16 + lane] : 0ull;
            int cum = 0, myw = -1, rem = 0;
            u64 myword = 0;
#pragma unroll
            for (int ww = 0; ww < 16; ++ww) {
                u64 wv = shfl_u64(w, ww);
                int pc = __popcll(wv);
                if (myw < 0 && lane < cum + pc) { myw = ww; rem = lane - cum; myword = wv; }
                cum += pc;
            }
            int n2 = cum;
            if (n2 == 0) continue;
            if (n2 > 64) { ovf = 1; continue; }   // benign race (all write 1)
            bool active = (lane < n2);
            int rank = 0;
            float ax1v = 0.f, ay1v = 0.f, ax2v = 0.f, ay2v = 0.f, arv = 0.f;
            if (active) {
                int pos = 0, r = rem;   // select rem-th set bit of myword
#pragma unroll
                for (int wd = 32; wd >= 1; wd >>= 1) {
                    u64 mask = ((1ull << wd) - 1ull) << pos;
                    int cc = __popcll(myword & mask);
                    if (r >= cc) { r -= cc; pos += wd; }
                }
                rank = myw * 64 + pos;
                float4 A = obx[rank]; float cA = oco[rank];
                ax1v = A.x + cA; ay1v = A.y + cA;
                ax2v = A.z + cA; ay2v = A.w + cA;
                arv = (ax2v - ax1v) * (ay2v - ay1v);
            }
            u64 alive = (n2 >= 64) ? ~0ull : ((1ull << n2) - 1ull);
            u64 kept = 0;
            while (alive) {
                int i = (int)__builtin_ctzll(alive);
                u64 bit = 1ull << i;
                kept |= bit;
                float bx1 = __shfl(ax1v, i), by1 = __shfl(ay1v, i);
                float bx2 = __shfl(ax2v, i), by2 = __shfl(ay2v, i);
                float bar = __shfl(arv, i);
                float ltx = fmaxf(bx1, ax1v), lty = fmaxf(by1, ay1v);
                float rbx = fminf(bx2, ax2v), rby = fminf(by2, ay2v);
                float ww2 = fmaxf(rbx - ltx, 0.0f), hh3 = fmaxf(rby - lty, 0.0f);
                float inter = ww2 * hh3;
                float iou = inter / (((bar + arv) - inter) + 1e-9f);
                u64 suppr = __ballot(iou > IOU_THR);
                alive &= ~(suppr | bit);
            }
            if (active) sup[rank] = ((kept >> lane) & 1ull) ? 0 : 1;
        }
    }
    __syncthreads();

    // exact serial fallback for classes with >64 candidates (P ~ 1e-40)
    if (ovf && t == 0) {
        for (int c2 = 0; c2 < NCLS; ++c2) {
            int n2 = 0;
            for (int w2 = 0; w2 < 16; ++w2) n2 += __popcll(bm[c2 * 16 + w2]);
            if (n2 <= 64) continue;
            for (int a2 = 0; a2 < NTOP; ++a2) {
                if (ocl[a2] != c2 || sup[a2]) continue;
                float4 A = obx[a2]; float cA = oco[a2];
                float ax1 = A.x + cA, ay1 = A.y + cA;
                float ax2 = A.z + cA, ay2 = A.w + cA;
                float areaA = (ax2 - ax1) * (ay2 - ay1);
                for (int d2 = a2 + 1; d2 < NTOP; ++d2) {
                    if (ocl[d2] != c2 || sup[d2]) continue;
                    float4 Bb = obx[d2];
                    float bx1 = Bb.x + cA, by1 = Bb.y + cA;
                    float bx2 = Bb.z + cA, by2 = Bb.w + cA;
                    float ltx = fmaxf(ax1, bx1), lty = fmaxf(ay1, by1);
                    float rbx = fminf(ax2, bx2), rby = fminf(ay2, by2);
                    float ww = fmaxf(rbx - ltx, 0.0f), hh3 = fmaxf(rby - lty, 0.0f);
                    float inter = ww * hh3;
                    float areaB = (bx2 - bx1) * (by2 - by1);
                    float iou = inter / (((areaA + areaB) - inter) + 1e-9f);
                    if (iou > IOU_THR) sup[d2] = 1;
                }
            }
        }
    }
    __syncthreads();

    // masked output write
    if (t < NTOP) {
        bool keep = (ocl[t] >= 0) && (sup[t] == 0);
        float4 o = obx[t];
        size_t d6 = ((size_t)b * NTOP + t) * 6;
        out[d6 + 0] = keep ? o.x : 0.0f;
        out[d6 + 1] = keep ? o.y : 0.0f;
        out[d6 + 2] = keep ? o.z : 0.0f;
        out[d6 + 3] = keep ? o.w : 0.0f;
        out[d6 + 4] = keep ? osc[t] : 0.0f;
        out[d6 + 5] = keep ? (float)ocl[t] : 0.0f;
    }
}

// ---------------------------------------------------------------------------
extern "C" void kernel_launch(void* const* d_in, const int* in_sizes, int n_in,
                              void* d_out, int out_size, void* d_ws, size_t ws_size,
                              hipStream_t stream) {
    const float* x = (const float*)d_in[0];
    char* ws = (char*)d_ws;
    float* msc = (float*)(ws);                       //      0 .. 806400
    int* cls = (int*)(ws + 806400);                  // 806400 .. 1612800

    k_score<<<NB * SBPB, 256, 0, stream>>>(x, msc, cls);
    k_fused<<<NB, 1024, 0, stream>>>(x, msc, cls, (float*)d_out);
}

// Round 8
// 144.094 us; speedup vs baseline: 1.0061x; 1.0061x over previous
//
#include <hip/hip_runtime.h>
#include <stdint.h>

#define NB 8
#define NPRED 25200
#define NTOP 1000
#define NCLS 80
#define CONF_T 0.25f
#define IOU_THR 0.45f
#define MAXWH 4096.0f
#define CAP 2048
#define NBINS 1025
#define SBLK 128
#define SBPB 197   // ceil(25200/128): 197*128 = 25216

typedef unsigned long long u64;

__device__ __forceinline__ u64 shfl_xor_u64(u64 v, int m) {
    int lo = __shfl_xor((int)(unsigned)v, m);
    int hi = __shfl_xor((int)(unsigned)(v >> 32), m);
    return ((u64)(unsigned)hi << 32) | (unsigned)lo;
}

// ---------------------------------------------------------------------------
// K1: score/class per pred + GLOBAL histogram of score bits (round-0 style:
// the ~150K global atomics hide under this kernel's memory-bound phase on
// 1576 blocks / 256 CUs — unlike k_fused's LDS pass A, which serialized
// ~19K DS-atomics on each of only 8 CUs).
// 256 threads / 128 preds: thread pair splits the 80-class argmax 40/40.
// Staging via global_load_lds width=16 (no VGPR round trip).
// ---------------------------------------------------------------------------
__global__ __launch_bounds__(256) void k_score(const float* __restrict__ x,
                                               float* __restrict__ msc,
                                               int* __restrict__ cls,
                                               unsigned* __restrict__ hist) {
#pragma clang fp contract(off)
    __shared__ __align__(16) float sm[SBLK * 85];
    const int b = blockIdx.x / SBPB;
    const int blk = blockIdx.x % SBPB;
    const int t = threadIdx.x;
    const int wave = t >> 6, lane = t & 63;
    const long long TOT4 = (long long)NB * NPRED * 85 / 4;  // 4,284,000
    const long long base4 = ((long long)b * NPRED + (long long)blk * SBLK) * 85 / 4;
    const float4* x4 = (const float4*)x;
    const int tile4 = SBLK * 85 / 4;  // 2720

    for (int k = 0; k < 11; ++k) {
        int ib = k * 256 + wave * 64;      // wave-uniform lds base (float4 units)
        int fi = ib + lane;
        if (fi < tile4) {
            long long gi = base4 + fi;
            if (gi >= TOT4) gi = TOT4 - 1;  // tail clamp (outputs guarded below)
            __builtin_amdgcn_global_load_lds(
                (const __attribute__((address_space(1))) void*)(x4 + gi),
                (__attribute__((address_space(3))) void*)(sm + (size_t)ib * 4),
                16, 0, 0);
        }
    }
    __syncthreads();

    const int p = t >> 1;        // pred within block [0,128)
    const int h = t & 1;         // class-half: 0 -> classes 0..39, 1 -> 40..79
    const int pred = blk * SBLK + p;
    const float* rowp = &sm[p * 85];
    float obj = rowp[4];
    const int cb = 5 + h * 40;
    float best = rowp[cb];
    int bid = h * 40;
    for (int c = 1; c < 40; ++c) {
        float v = rowp[cb + c];
        if (v > best) { best = v; bid = h * 40 + c; }  // strict >: first occurrence
    }
    float obest = __shfl_xor(best, 1);
    int obid = __shfl_xor(bid, 1);
    if (h == 0 && pred < NPRED) {
        float fb = best; int fc = bid;
        if (obest > fb) { fb = obest; fc = obid; }  // ties -> lower class idx (h=0)
        float score = obj * fb;
        int q = b * NPRED + pred;
        msc[q] = (score > CONF_T) ? score : -1.0f;
        cls[q] = fc;
        if (score > CONF_T) {
            int bin = (int)(__float_as_uint(score) >> 14) - 0xFA00;
            bin = bin < 0 ? 0 : (bin > 1024 ? 1024 : bin);
            atomicAdd(&hist[b * NBINS + bin], 1u);
        }
    }
}

// ---------------------------------------------------------------------------
// K2 (fused tail) = round-5 k_fused (best profiled: 47.8 us) MINUS pass A:
// the histogram arrives precomputed in global memory (L2-hot); wave 0 reads
// it directly for the boundary-bin search. No LDS hh array, no zero-init,
// no ~19K LDS atomicAdds on this 8-CU kernel. Everything downstream --
// sv-stash, pass-B compaction, 2048 hybrid bitonic, u32 class-grouping
// sort, one-wave-per-class ballot greedy, fallbacks -- is round-5 verbatim.
// Exactness unchanged (cross-class IoU exactly 0; same-class IoU identical
// expression; absmax 0.0 for 8 rounds).
// ---------------------------------------------------------------------------
__global__ __launch_bounds__(1024) void k_fused(const float* __restrict__ x,
                                                const float* __restrict__ msc,
                                                const int* __restrict__ cls,
                                                const unsigned* __restrict__ hist,
                                                float* __restrict__ out) {
#pragma clang fp contract(off)
    __shared__ __align__(16) unsigned char uni[CAP * 8];  // keys | keys32+seg+sup
    __shared__ __align__(16) float4 obx[NTOP];   // un-offset xyxy
    __shared__ float oco[NTOP];                  // cls * 4096
    __shared__ float osc[NTOP];                  // score
    __shared__ int   ocl[NTOP];                  // class id, -1 if invalid
    __shared__ int sB;
    __shared__ unsigned lcnt;
    __shared__ int ovf;
    u64* keys = (u64*)uni;
    const int b = blockIdx.x, t = threadIdx.x;
    const float* ms = msc + (size_t)b * NPRED;

    // single global pass: stash msc in registers (25*1024 = 25600 >= 25200)
    float sv[25];
#pragma unroll
    for (int k = 0; k < 25; ++k) {
        int p = t + k * 1024;
        sv[k] = (p < NPRED) ? ms[p] : -1.0f;
    }

    if (t == 0) { lcnt = 0; ovf = 0; }

    if (t < 64) {  // wave 0: suffix-count boundary bin B from GLOBAL hist
        const int lane = t;
        const unsigned* h = hist + b * NBINS;
        const int hi2 = 1024 - 16 * lane;       // lane chunk: bins [hi2-15, hi2]
        unsigned sum = 0;
        for (int k = 0; k < 16; ++k) sum += h[hi2 - k];
        if (lane == 63) sum += h[0];
        unsigned v = sum;
        for (int d = 1; d < 64; d <<= 1) {
            unsigned o = __shfl_up(v, d);
            if (lane >= d) v += o;
        }
        unsigned excl = v - sum;                // count strictly above my chunk
        u64 ball = __ballot(v >= NTOP);
        int B = 0;
        if (ball != 0) {
            int sel = __builtin_ctzll(ball);
            if (lane == sel) {
                unsigned run = excl;
                for (int k = 0; k < 16; ++k) {
                    run += h[hi2 - k];
                    if (run >= NTOP) { B = hi2 - k; break; }
                }
            }
            B = __shfl(B, sel);
        }
        if (lane == 0) sB = B;
    }
    __syncthreads();
    const int B = sB;

    // pass B: compact candidates (bin >= B) into LDS keys (from regs)
#pragma unroll
    for (int k = 0; k < 25; ++k) {
        float s = sv[k];
        if (s > CONF_T) {
            unsigned bits = __float_as_uint(s);
            int bin = (int)(bits >> 14) - 0xFA00;
            bin = bin < 0 ? 0 : (bin > 1024 ? 1024 : bin);
            if (bin >= B) {
                unsigned slot = atomicAdd(&lcnt, 1u);
                if (slot < CAP)
                    keys[slot] = ((u64)(~bits) << 32) | (unsigned)(t + k * 1024);
            }
        }
    }
    __syncthreads();
    unsigned c = lcnt; if (c > CAP) c = CAP;
    for (int i = (int)c + t; i < CAP; i += 1024) keys[i] = ~0ULL;
    __syncthreads();

    // ---- hybrid bitonic sort, CAP=2048 u64 keys ascending ----
    const unsigned ia = (((unsigned)t & ~63u) << 1) | ((unsigned)t & 63u);
    const unsigned ib = ia + 64u;

    auto ce = [&](u64& v, unsigned i, unsigned j, unsigned k) {
        u64 pv = shfl_xor_u64(v, (int)j);
        bool asc = ((i & k) == 0u);
        bool lower = ((i & j) == 0u);
        bool takeMin = (asc == lower);
        bool less = (v < pv);
        v = (takeMin == less) ? v : pv;
    };

    {   // phase 1: k = 2..64 entirely in registers
        u64 a = keys[ia], d = keys[ib];
        for (unsigned k = 2; k <= 64; k <<= 1)
            for (unsigned j = k >> 1; j >= 1; j >>= 1) {
                ce(a, ia, j, k);
                ce(d, ib, j, k);
            }
        keys[ia] = a; keys[ib] = d;
    }
    __syncthreads();

    // phase 2: k = 128..2048; j>=64 in LDS, j<=32 in registers
    for (unsigned k = 128; k <= CAP; k <<= 1) {
        for (unsigned j = k >> 1; j >= 64; j >>= 1) {
            unsigned i = (((unsigned)t & ~(j - 1)) << 1) | ((unsigned)t & (j - 1));
            unsigned pi = i | j;
            bool up = ((i & k) == 0);
            u64 a = keys[i], d = keys[pi];
            bool sw = up ? (a > d) : (a < d);
            if (sw) { keys[i] = d; keys[pi] = a; }
            __syncthreads();
        }
        u64 a = keys[ia], d = keys[ib];
        for (unsigned j = 32; j >= 1; j >>= 1) {
            ce(a, ia, j, k);
            ce(d, ib, j, k);
        }
        keys[ia] = a; keys[ib] = d;
        __syncthreads();
    }

    // gather top-1000 into LDS SoA
    if (t < NTOP) {
        u64 key = keys[t];
        unsigned p = (unsigned)key;
        float score = __uint_as_float(~(unsigned)(key >> 32));
        bool v = score > CONF_T;
        float4 o = make_float4(0.f, 0.f, 0.f, 0.f);
        float co = 0.f; int cid = -1;
        if (v) {
            const float* xp = x + ((size_t)b * NPRED + p) * 85;
            float xc = xp[0], yc = xp[1], w = xp[2], h = xp[3];
            float hw = w * 0.5f, hh2 = h * 0.5f;
            o.x = xc - hw; o.y = yc - hh2; o.z = xc + hw; o.w = yc + hh2;
            cid = cls[(size_t)b * NPRED + p];
            co = (float)cid * MAXWH;
        }
        obx[t] = o; oco[t] = co; osc[t] = score; ocl[t] = cid;
    }
    __syncthreads();    // u64 keys dead; overlay keys32/clsStart/clsEnd/sup

    unsigned* keys32 = (unsigned*)uni;              // 1024 u32   (4096 B)
    int* clsStart = (int*)(uni + 4096);             // 80 ints
    int* clsEnd = (int*)(uni + 4416);               // 80 ints
    unsigned char* sup = uni + 4736;                // 1000 B

    // ---- class-grouping sort: key32 = (cls<<10)|rank, 1024 elems, 1 per thread
    unsigned v32 = (t < NTOP && ocl[t] >= 0)
                       ? (((unsigned)ocl[t] << 10) | (unsigned)t) : 0xFFFFFFFFu;

    auto ce32 = [&](unsigned& v, unsigned j, unsigned k) {
        unsigned pv = (unsigned)__shfl_xor((int)v, (int)j);
        bool asc = (((unsigned)t & k) == 0u);
        bool lower = (((unsigned)t & j) == 0u);
        bool takeMin = (asc == lower);
        v = ((v < pv) == takeMin) ? v : pv;
    };

    for (unsigned k = 2; k <= 64; k <<= 1)          // intra-wave levels
        for (unsigned j = k >> 1; j >= 1; j >>= 1) ce32(v32, j, k);

    for (unsigned k = 128; k <= 1024; k <<= 1) {
        for (unsigned j = k >> 1; j >= 64; j >>= 1) {   // LDS levels (stride-1)
            keys32[t] = v32;
            __syncthreads();
            unsigned pv = keys32[t ^ j];
            bool asc = (((unsigned)t & k) == 0u);
            bool lower = (((unsigned)t & j) == 0u);
            bool takeMin = (asc == lower);
            v32 = ((v32 < pv) == takeMin) ? v32 : pv;
            __syncthreads();
        }
        for (unsigned j = 32; j >= 1; j >>= 1) ce32(v32, j, k);
    }
    if (t < NTOP) sup[t] = 0;
    if (t < NCLS) { clsStart[t] = 0; clsEnd[t] = 0; }
    keys32[t] = v32;
    __syncthreads();

    // segment boundaries (valid keys are contiguous at the front)
    {
        unsigned kk = keys32[t];
        if (kk != 0xFFFFFFFFu) {
            int c2 = (int)(kk >> 10);
            unsigned prev = (t > 0) ? keys32[t - 1] : 0xFFFFFFFFu;
            if (t == 0 || (int)(prev >> 10) != c2) clsStart[c2] = t;
            unsigned nxt = (t < 1023) ? keys32[t + 1] : 0xFFFFFFFFu;
            if (t == 1023 || (int)(nxt >> 10) != c2) clsEnd[c2] = t + 1;
        }
    }
    __syncthreads();

    // ---- per-class ballot greedy: one wave per class, 5 rounds ----
    {
        const int waveId = t >> 6, lane2 = t & 63;
        for (int c2 = waveId; c2 < NCLS; c2 += 16) {
            int s2 = clsStart[c2];
            int n2 = clsEnd[c2] - s2;
            if (n2 <= 0) continue;
            if (n2 > 64) { ovf = 1; continue; }
            int rank = 0;
            float ax1v = 0.f, ay1v = 0.f, ax2v = 0.f, ay2v = 0.f, arv = 0.f;
            if (lane2 < n2) {
                rank = (int)(keys32[s2 + lane2] & 1023u);
                float4 A = obx[rank]; float cA = oco[rank];
                ax1v = A.x + cA; ay1v = A.y + cA;
                ax2v = A.z + cA; ay2v = A.w + cA;
                arv = (ax2v - ax1v) * (ay2v - ay1v);
            }
            u64 alive = (n2 >= 64) ? ~0ull : ((1ull << n2) - 1ull);
            u64 kept = 0;
            while (alive) {
                int i = (int)__builtin_ctzll(alive);
                u64 bit = 1ull << i;
                kept |= bit;
                float bx1 = __shfl(ax1v, i), by1 = __shfl(ay1v, i);
                float bx2 = __shfl(ax2v, i), by2 = __shfl(ay2v, i);
                float bar = __shfl(arv, i);
                float ltx = fmaxf(bx1, ax1v), lty = fmaxf(by1, ay1v);
                float rbx = fminf(bx2, ax2v), rby = fminf(by2, ay2v);
                float ww = fmaxf(rbx - ltx, 0.0f), hh3 = fmaxf(rby - lty, 0.0f);
                float inter = ww * hh3;
                float iou = inter / (((bar + arv) - inter) + 1e-9f);
                u64 suppr = __ballot(iou > IOU_THR);
                alive &= ~(suppr | bit);
            }
            if (lane2 < n2) sup[rank] = ((kept >> lane2) & 1ull) ? 0 : 1;
        }
    }
    __syncthreads();

    // exact serial fallback for classes with >64 candidates (P ~ 1e-40)
    if (ovf && t == 0) {
        for (int c2 = 0; c2 < NCLS; ++c2) {
            int s2 = clsStart[c2], e2 = clsEnd[c2];
            if (e2 - s2 <= 64) continue;
            for (int a2 = s2; a2 < e2; ++a2) {
                int ra = (int)(keys32[a2] & 1023u);
                if (sup[ra]) continue;
                float4 A = obx[ra]; float cA = oco[ra];
                float ax1 = A.x + cA, ay1 = A.y + cA;
                float ax2 = A.z + cA, ay2 = A.w + cA;
                float areaA = (ax2 - ax1) * (ay2 - ay1);
                for (int d2 = a2 + 1; d2 < e2; ++d2) {
                    int rd = (int)(keys32[d2] & 1023u);
                    if (sup[rd]) continue;
                    float4 Bb = obx[rd];
                    float bx1 = Bb.x + cA, by1 = Bb.y + cA;
                    float bx2 = Bb.z + cA, by2 = Bb.w + cA;
                    float ltx = fmaxf(ax1, bx1), lty = fmaxf(ay1, by1);
                    float rbx = fminf(ax2, bx2), rby = fminf(ay2, by2);
                    float ww = fmaxf(rbx - ltx, 0.0f), hh3 = fmaxf(rby - lty, 0.0f);
                    float inter = ww * hh3;
                    float areaB = (bx2 - bx1) * (by2 - by1);
                    float iou = inter / (((areaA + areaB) - inter) + 1e-9f);
                    if (iou > IOU_THR) sup[rd] = 1;
                }
            }
        }
    }
    __syncthreads();

    // masked output write
    if (t < NTOP) {
        bool keep = (ocl[t] >= 0) && (sup[t] == 0);
        float4 o = obx[t];
        size_t d6 = ((size_t)b * NTOP + t) * 6;
        out[d6 + 0] = keep ? o.x : 0.0f;
        out[d6 + 1] = keep ? o.y : 0.0f;
        out[d6 + 2] = keep ? o.z : 0.0f;
        out[d6 + 3] = keep ? o.w : 0.0f;
        out[d6 + 4] = keep ? osc[t] : 0.0f;
        out[d6 + 5] = keep ? (float)ocl[t] : 0.0f;
    }
}

// ---------------------------------------------------------------------------
extern "C" void kernel_launch(void* const* d_in, const int* in_sizes, int n_in,
                              void* d_out, int out_size, void* d_ws, size_t ws_size,
                              hipStream_t stream) {
    const float* x = (const float*)d_in[0];
    char* ws = (char*)d_ws;
    float* msc = (float*)(ws);                       //       0 .. 806400
    int* cls = (int*)(ws + 806400);                  //  806400 .. 1612800
    unsigned* hist = (unsigned*)(ws + 1612800);      // 1612800 .. 1645600 (8*1025*4)

    hipMemsetAsync(hist, 0, NB * NBINS * 4, stream);
    k_score<<<NB * SBPB, 256, 0, stream>>>(x, msc, cls, hist);
    k_fused<<<NB, 1024, 0, stream>>>(x, msc, cls, hist, (float*)d_out);
}

// Round 10
// 129.246 us; speedup vs baseline: 1.1217x; 1.1149x over previous
//
#include <hip/hip_runtime.h>
#include <stdint.h>

#define NB 8
#define NPRED 25200
#define NTOP 1000
#define NCLS 80
#define CONF_T 0.25f
#define IOU_THR 0.45f
#define MAXWH 4096.0f
#define CAP 2048
#define NBINS 1025
#define SBLK 128
#define SBPB 197   // ceil(25200/128): 197*128 = 25216

typedef unsigned long long u64;

__device__ __forceinline__ u64 shfl_u64(u64 v, int src) {
    int lo = __shfl((int)(unsigned)v, src);
    int hi = __shfl((int)(unsigned)(v >> 32), src);
    return ((u64)(unsigned)hi << 32) | (unsigned)lo;
}

// ---------------------------------------------------------------------------
// K1: score/class per pred (rounds 3-7 version; no histogram, no atomics).
// 256 threads / 128 preds: thread pair splits the 80-class argmax 40/40.
// Staging via global_load_lds width=16 (no VGPR round trip).
// ---------------------------------------------------------------------------
__global__ __launch_bounds__(256) void k_score(const float* __restrict__ x,
                                               float* __restrict__ msc,
                                               int* __restrict__ cls) {
#pragma clang fp contract(off)
    __shared__ __align__(16) float sm[SBLK * 85];
    const int b = blockIdx.x / SBPB;
    const int blk = blockIdx.x % SBPB;
    const int t = threadIdx.x;
    const int wave = t >> 6, lane = t & 63;
    const long long TOT4 = (long long)NB * NPRED * 85 / 4;  // 4,284,000
    const long long base4 = ((long long)b * NPRED + (long long)blk * SBLK) * 85 / 4;
    const float4* x4 = (const float4*)x;
    const int tile4 = SBLK * 85 / 4;  // 2720

    for (int k = 0; k < 11; ++k) {
        int ib = k * 256 + wave * 64;      // wave-uniform lds base (float4 units)
        int fi = ib + lane;
        if (fi < tile4) {
            long long gi = base4 + fi;
            if (gi >= TOT4) gi = TOT4 - 1;  // tail clamp (outputs guarded below)
            __builtin_amdgcn_global_load_lds(
                (const __attribute__((address_space(1))) void*)(x4 + gi),
                (__attribute__((address_space(3))) void*)(sm + (size_t)ib * 4),
                16, 0, 0);
        }
    }
    __syncthreads();

    const int p = t >> 1;        // pred within block [0,128)
    const int h = t & 1;         // class-half: 0 -> classes 0..39, 1 -> 40..79
    const int pred = blk * SBLK + p;
    const float* rowp = &sm[p * 85];
    float obj = rowp[4];
    const int cb = 5 + h * 40;
    float best = rowp[cb];
    int bid = h * 40;
    for (int c = 1; c < 40; ++c) {
        float v = rowp[cb + c];
        if (v > best) { best = v; bid = h * 40 + c; }  // strict >: first occurrence
    }
    float obest = __shfl_xor(best, 1);
    int obid = __shfl_xor(bid, 1);
    if (h == 0 && pred < NPRED) {
        float fb = best; int fc = bid;
        if (obest > fb) { fb = obest; fc = obid; }  // ties -> lower class idx (h=0)
        float score = obj * fb;
        int q = b * NPRED + pred;
        msc[q] = (score > CONF_T) ? score : -1.0f;
        cls[q] = fc;
    }
}

// ---------------------------------------------------------------------------
// K2 (fused tail), round 10 (= round-9 source; round-9 bench died on an
// INFRA error "container failed twice" with no counters -- resubmitting
// unchanged keeps the r8->r9 experiment valid; kernel audited: all loops
// bounded, LDS ~61 KB, no OOB). NO SORTS. Cross-round ledger: every
// variant keeping a full bitonic landed 46-66 us profiled (r5 47.8,
// r6 65.7, r7 59.1, r8 46.3) -- the ~40 barriers + ~150 CE levels are the
// cost, not pass A (r8 proved pass A ~= 1.5 us). Rank is computed DIRECTLY:
//   1. pass A: 1025-bin LDS histogram of score bits (round-5 verbatim).
//   2. wave 0: suffix-scan -> hbase[bin] = #candidates strictly above bin
//      (exact rank base), + boundary bin B (round-5 search logic).
//   3. pass B: scatter slot = atomicAdd(&hbase[bin],1) -> bin-grouped keys.
//   4. rank: each candidate counts same-bin keys < its key (segment ~25
//      wide near the cut; fully parallel, NO dependent chains -- round 7's
//      mistake was a serial insertion-sort cleanup here) and writes
//      ksort[base + count] if < 1000. Keys unique (idx low bits) -> exact
//      permutation; ties resolve idx-ascending = stable top_k.
//   5. gather + bm[80][16] rank-bitmask + one-wave-per-class ballot greedy
//      (round-7 verbatim, absmax 0.0) + masked write.
// 8 barriers total (was ~40). Exactness unchanged: cross-class IoU exactly
// 0; same-class IoU identical expression; absmax 0.0 for 9 rounds.
// CAP-drop (slot>=2048) remains the same impossible-tier semantics.
// ---------------------------------------------------------------------------
__global__ __launch_bounds__(1024) void k_fused(const float* __restrict__ x,
                                                const float* __restrict__ msc,
                                                const int* __restrict__ cls,
                                                float* __restrict__ out) {
#pragma clang fp contract(off)
    __shared__ __align__(16) unsigned char uni[CAP * 8];  // keys | bm+sup
    __shared__ unsigned hh[NBINS];       // pass-A counts (persist for rank)
    __shared__ unsigned hbase[NBINS];    // suffix bases -> scatter cursors
    __shared__ __align__(16) u64 ksort[NTOP];
    __shared__ __align__(16) float4 obx[NTOP];   // un-offset xyxy
    __shared__ float oco[NTOP];                  // cls * 4096
    __shared__ float osc[NTOP];                  // score
    __shared__ int   ocl[NTOP];                  // class id, -1 if invalid
    __shared__ int sB;
    __shared__ int ovf;
    u64* keys = (u64*)uni;
    const int b = blockIdx.x, t = threadIdx.x;
    const float* ms = msc + (size_t)b * NPRED;

    // single global pass: stash msc in registers (25*1024 = 25600 >= 25200)
    float sv[25];
#pragma unroll
    for (int k = 0; k < 25; ++k) {
        int p = t + k * 1024;
        sv[k] = (p < NPRED) ? ms[p] : -1.0f;
    }

    for (int i = t; i < NBINS; i += 1024) hh[i] = 0;
    keys[t] = ~0ULL; keys[t + 1024] = ~0ULL;
    if (t < NTOP) ksort[t] = ~0ULL;
    if (t == 0) { ovf = 0; sB = 0; }
    __syncthreads();

    // pass A: per-batch histogram of score bits (LDS atomics, from regs)
#pragma unroll
    for (int k = 0; k < 25; ++k) {
        float s = sv[k];
        if (s > CONF_T) {
            unsigned bits = __float_as_uint(s);
            int bin = (int)(bits >> 14) - 0xFA00;
            bin = bin < 0 ? 0 : (bin > 1024 ? 1024 : bin);
            atomicAdd(&hh[bin], 1u);
        }
    }
    __syncthreads();

    if (t < 64) {  // wave 0: suffix bases for ALL bins + boundary bin B
        const int lane = t;
        const int hi2 = 1024 - 16 * lane;       // lane chunk: bins [hi2-15, hi2]
        unsigned lc[16];
        unsigned sum = 0;
#pragma unroll
        for (int k = 0; k < 16; ++k) { lc[k] = hh[hi2 - k]; sum += lc[k]; }
        if (lane == 63) sum += hh[0];
        unsigned v = sum;
        for (int d = 1; d < 64; d <<= 1) {
            unsigned o = __shfl_up(v, d);
            if (lane >= d) v += o;
        }
        unsigned excl = v - sum;                // count strictly above my chunk
        // per-bin rank bases: hbase[bin] = #candidates in bins > bin
        unsigned run = excl;
#pragma unroll
        for (int k = 0; k < 16; ++k) { hbase[hi2 - k] = run; run += lc[k]; }
        if (lane == 63) hbase[0] = run;         // bin 0 (run excludes hh[0])
        // boundary bin B (round-5 logic)
        u64 ball = __ballot(v >= NTOP);
        int B = 0;
        if (ball != 0) {
            int sel = __builtin_ctzll(ball);
            if (lane == sel) {
                unsigned r2 = excl;
                for (int k = 0; k < 16; ++k) {
                    r2 += lc[k];
                    if (r2 >= NTOP) { B = hi2 - k; break; }
                }
            }
            B = __shfl(B, sel);
        }
        if (lane == 0) sB = B;
    }
    __syncthreads();
    const int B = sB;

    // pass B: scatter candidates (bin >= B) to their bin segment
#pragma unroll
    for (int k = 0; k < 25; ++k) {
        float s = sv[k];
        if (s > CONF_T) {
            unsigned bits = __float_as_uint(s);
            int bin = (int)(bits >> 14) - 0xFA00;
            bin = bin < 0 ? 0 : (bin > 1024 ? 1024 : bin);
            if (bin >= B) {
                unsigned slot = atomicAdd(&hbase[bin], 1u);
                if (slot < (unsigned)CAP)
                    keys[slot] = ((u64)(~bits) << 32) | (unsigned)(t + k * 1024);
            }
        }
    }
    __syncthreads();

    // rank: exact global rank = segment base + #{same-bin keys < mine}
    {
        auto binOf = [](u64 kk) -> int {
            unsigned bits = ~(unsigned)(kk >> 32);
            int bin = (int)(bits >> 14) - 0xFA00;
            return bin < 0 ? 0 : (bin > 1024 ? 1024 : bin);
        };
#pragma unroll
        for (int pp = 0; pp < 2; ++pp) {
            int i = t + pp * 1024;
            u64 my = keys[i];
            if (my == ~0ULL) continue;
            int bin = binOf(my);
            int e2 = (int)hbase[bin];           // base + n (post-scatter cursor)
            if (e2 > CAP) e2 = CAP;
            int base = e2 - (int)hh[bin];
            if (base < 0) base = 0;
            unsigned r = (unsigned)base;
            for (int j = base; j < e2; ++j) r += (keys[j] < my) ? 1u : 0u;
            if (r < (unsigned)NTOP) ksort[r] = my;
        }
    }
    __syncthreads();

    // gather top-1000 into LDS SoA; zero bm/sup (keys region is dead)
    u64* bm = (u64*)uni;                  // [80][16] u64 = 10240 B
    unsigned char* sup = uni + 10240;     // 1000 B
    for (int i = t; i < NCLS * 16; i += 1024) bm[i] = 0;
    if (t < NTOP) {
        sup[t] = 0;
        u64 key = ksort[t];
        unsigned p = (unsigned)key;
        float score = __uint_as_float(~(unsigned)(key >> 32));
        bool vd = score > CONF_T;
        float4 o = make_float4(0.f, 0.f, 0.f, 0.f);
        float co = 0.f; int cid = -1;
        if (vd) {
            const float* xp = x + ((size_t)b * NPRED + p) * 85;
            float xc = xp[0], yc = xp[1], w = xp[2], h = xp[3];
            float hw = w * 0.5f, hh2 = h * 0.5f;
            o.x = xc - hw; o.y = yc - hh2; o.z = xc + hw; o.w = yc + hh2;
            cid = cls[(size_t)b * NPRED + p];
            co = (float)cid * MAXWH;
        }
        obx[t] = o; oco[t] = co; osc[t] = score; ocl[t] = cid;
    }
    __syncthreads();
    if (t < NTOP && ocl[t] >= 0)
        atomicOr(&bm[ocl[t] * 16 + (t >> 6)], 1ull << (t & 63));
    __syncthreads();

    // ---- per-class ballot greedy: one wave per class, lane = rank order ----
    {
        const int wave = t >> 6, lane = t & 63;
        for (int c2 = wave; c2 < NCLS; c2 += 16) {
            u64 w = (lane < 16) ? bm[c2 * 16 + lane] : 0ull;
            int cum = 0, myw = -1, rem = 0;
            u64 myword = 0;
#pragma unroll
            for (int ww = 0; ww < 16; ++ww) {
                u64 wv = shfl_u64(w, ww);
                int pc = __popcll(wv);
                if (myw < 0 && lane < cum + pc) { myw = ww; rem = lane - cum; myword = wv; }
                cum += pc;
            }
            int n2 = cum;
            if (n2 == 0) continue;
            if (n2 > 64) { ovf = 1; continue; }   // benign race (all write 1)
            bool active = (lane < n2);
            int rank = 0;
            float ax1v = 0.f, ay1v = 0.f, ax2v = 0.f, ay2v = 0.f, arv = 0.f;
            if (active) {
                int pos = 0, r = rem;   // select rem-th set bit of myword
#pragma unroll
                for (int wd = 32; wd >= 1; wd >>= 1) {
                    u64 mask = ((1ull << wd) - 1ull) << pos;
                    int cc = __popcll(myword & mask);
                    if (r >= cc) { r -= cc; pos += wd; }
                }
                rank = myw * 64 + pos;
                float4 A = obx[rank]; float cA = oco[rank];
                ax1v = A.x + cA; ay1v = A.y + cA;
                ax2v = A.z + cA; ay2v = A.w + cA;
                arv = (ax2v - ax1v) * (ay2v - ay1v);
            }
            u64 alive = (n2 >= 64) ? ~0ull : ((1ull << n2) - 1ull);
            u64 kept = 0;
            while (alive) {
                int i = (int)__builtin_ctzll(alive);
                u64 bit = 1ull << i;
                kept |= bit;
                float bx1 = __shfl(ax1v, i), by1 = __shfl(ay1v, i);
                float bx2 = __shfl(ax2v, i), by2 = __shfl(ay2v, i);
                float bar = __shfl(arv, i);
                float ltx = fmaxf(bx1, ax1v), lty = fmaxf(by1, ay1v);
                float rbx = fminf(bx2, ax2v), rby = fminf(by2, ay2v);
                float ww2 = fmaxf(rbx - ltx, 0.0f), hh3 = fmaxf(rby - lty, 0.0f);
                float inter = ww2 * hh3;
                float iou = inter / (((bar + arv) - inter) + 1e-9f);
                u64 suppr = __ballot(iou > IOU_THR);
                alive &= ~(suppr | bit);
            }
            if (active) sup[rank] = ((kept >> lane) & 1ull) ? 0 : 1;
        }
    }
    __syncthreads();

    // exact serial fallback for classes with >64 candidates (P ~ 1e-40)
    if (ovf && t == 0) {
        for (int c2 = 0; c2 < NCLS; ++c2) {
            int n2 = 0;
            for (int w2 = 0; w2 < 16; ++w2) n2 += __popcll(bm[c2 * 16 + w2]);
            if (n2 <= 64) continue;
            for (int a2 = 0; a2 < NTOP; ++a2) {
                if (ocl[a2] != c2 || sup[a2]) continue;
                float4 A = obx[a2]; float cA = oco[a2];
                float ax1 = A.x + cA, ay1 = A.y + cA;
                float ax2 = A.z + cA, ay2 = A.w + cA;
                float areaA = (ax2 - ax1) * (ay2 - ay1);
                for (int d2 = a2 + 1; d2 < NTOP; ++d2) {
                    if (ocl[d2] != c2 || sup[d2]) continue;
                    float4 Bb = obx[d2];
                    float bx1 = Bb.x + cA, by1 = Bb.y + cA;
                    float bx2 = Bb.z + cA, by2 = Bb.w + cA;
                    float ltx = fmaxf(ax1, bx1), lty = fmaxf(ay1, by1);
                    float rbx = fminf(ax2, bx2), rby = fminf(ay2, by2);
                    float ww = fmaxf(rbx - ltx, 0.0f), hh3 = fmaxf(rby - lty, 0.0f);
                    float inter = ww * hh3;
                    float areaB = (bx2 - bx1) * (by2 - by1);
                    float iou = inter / (((areaA + areaB) - inter) + 1e-9f);
                    if (iou > IOU_THR) sup[d2] = 1;
                }
            }
        }
    }
    __syncthreads();

    // masked output write
    if (t < NTOP) {
        bool keep = (ocl[t] >= 0) && (sup[t] == 0);
        float4 o = obx[t];
        size_t d6 = ((size_t)b * NTOP + t) * 6;
        out[d6 + 0] = keep ? o.x : 0.0f;
        out[d6 + 1] = keep ? o.y : 0.0f;
        out[d6 + 2] = keep ? o.z : 0.0f;
        out[d6 + 3] = keep ? o.w : 0.0f;
        out[d6 + 4] = keep ? osc[t] : 0.0f;
        out[d6 + 5] = keep ? (float)ocl[t] : 0.0f;
    }
}

// ---------------------------------------------------------------------------
extern "C" void kernel_launch(void* const* d_in, const int* in_sizes, int n_in,
                              void* d_out, int out_size, void* d_ws, size_t ws_size,
                              hipStream_t stream) {
    const float* x = (const float*)d_in[0];
    char* ws = (char*)d_ws;
    float* msc = (float*)(ws);                       //      0 .. 806400
    int* cls = (int*)(ws + 806400);                  // 806400 .. 1612800

    k_score<<<NB * SBPB, 256, 0, stream>>>(x, msc, cls);
    k_fused<<<NB, 1024, 0, stream>>>(x, msc, cls, (float*)d_out);
}

// Round 11
// 127.919 us; speedup vs baseline: 1.1333x; 1.0104x over previous
//
#include <hip/hip_runtime.h>
#include <stdint.h>

#define NB 8
#define NPRED 25200
#define NTOP 1000
#define NCLS 80
#define CONF_T 0.25f
#define IOU_THR 0.45f
#define MAXWH 4096.0f
#define CAP 2048
#define NBINS 1025
#define SBLK 128
#define SBPB 197   // ceil(25200/128): 197*128 = 25216

typedef unsigned long long u64;

__device__ __forceinline__ u64 shfl_u64(u64 v, int src) {
    int lo = __shfl((int)(unsigned)v, src);
    int hi = __shfl((int)(unsigned)(v >> 32), src);
    return ((u64)(unsigned)hi << 32) | (unsigned)lo;
}

// ---------------------------------------------------------------------------
// K1: score/class per pred (unchanged from round 10 / best-total lineage).
// 256 threads / 128 preds: thread pair splits the 80-class argmax 40/40.
// Staging via global_load_lds width=16 (no VGPR round trip).
// ---------------------------------------------------------------------------
__global__ __launch_bounds__(256) void k_score(const float* __restrict__ x,
                                               float* __restrict__ msc,
                                               int* __restrict__ cls) {
#pragma clang fp contract(off)
    __shared__ __align__(16) float sm[SBLK * 85];
    const int b = blockIdx.x / SBPB;
    const int blk = blockIdx.x % SBPB;
    const int t = threadIdx.x;
    const int wave = t >> 6, lane = t & 63;
    const long long TOT4 = (long long)NB * NPRED * 85 / 4;  // 4,284,000
    const long long base4 = ((long long)b * NPRED + (long long)blk * SBLK) * 85 / 4;
    const float4* x4 = (const float4*)x;
    const int tile4 = SBLK * 85 / 4;  // 2720

    for (int k = 0; k < 11; ++k) {
        int ib = k * 256 + wave * 64;      // wave-uniform lds base (float4 units)
        int fi = ib + lane;
        if (fi < tile4) {
            long long gi = base4 + fi;
            if (gi >= TOT4) gi = TOT4 - 1;  // tail clamp (outputs guarded below)
            __builtin_amdgcn_global_load_lds(
                (const __attribute__((address_space(1))) void*)(x4 + gi),
                (__attribute__((address_space(3))) void*)(sm + (size_t)ib * 4),
                16, 0, 0);
        }
    }
    __syncthreads();

    const int p = t >> 1;        // pred within block [0,128)
    const int h = t & 1;         // class-half: 0 -> classes 0..39, 1 -> 40..79
    const int pred = blk * SBLK + p;
    const float* rowp = &sm[p * 85];
    float obj = rowp[4];
    const int cb = 5 + h * 40;
    float best = rowp[cb];
    int bid = h * 40;
    for (int c = 1; c < 40; ++c) {
        float v = rowp[cb + c];
        if (v > best) { best = v; bid = h * 40 + c; }  // strict >: first occurrence
    }
    float obest = __shfl_xor(best, 1);
    int obid = __shfl_xor(bid, 1);
    if (h == 0 && pred < NPRED) {
        float fb = best; int fc = bid;
        if (obest > fb) { fb = obest; fc = obid; }  // ties -> lower class idx (h=0)
        float score = obj * fb;
        int q = b * NPRED + pred;
        msc[q] = (score > CONF_T) ? score : -1.0f;
        cls[q] = fc;
    }
}

// ---------------------------------------------------------------------------
// K2 (fused tail), round 11 = round-10 rank-direct structure (best TOTAL,
// 129.2 us; profiled per-dispatch durations shown non-correlated with the
// timed total across r5-r10 -> totals are the only ground truth) with three
// issue/latency reductions:
//  - msc stash vectorized float4 (G13): 25 scalar -> 7 x 16B loads/thread
//    (25200 = 6300 float4 exactly; both passes consume from registers).
//  - rank+gather FUSED: the rank-owner gathers its candidate's x-row into
//    SoA[r] directly. Deletes ksort (8 KB) and one barrier; the 5 scattered
//    global loads are issued BEFORE the ~25-iteration LDS count loop
//    (address depends only on the key), hiding their latency under it.
//  - only ocl/sup need init (-1/0): other SoA defaults are dead under the
//    keep=false cndmask in the output write.
// Pipeline: pass A 1025-bin LDS hist -> wave-0 suffix-scan (exact per-bin
// rank bases hbase[] + boundary bin B) -> scatter slot=atomicAdd(hbase) ->
// fused rank(+gather): r = base + #{same-bin keys < mine} (segments ~25
// wide, fully parallel, no dependent chains) -> bm[80][16] rank bitmask ->
// one-wave-per-class ballot greedy -> masked write.
// Exactness unchanged: keys unique -> rank is an exact permutation, ties
// idx-ascending = stable top_k; cross-class IoU exactly 0 (stripes 4094
// apart -> clipped wh=0); same-class IoU identical expression; absmax 0.0
// for 10 rounds. CAP-drop + >64-per-class fallback semantics unchanged.
// ---------------------------------------------------------------------------
__global__ __launch_bounds__(1024) void k_fused(const float* __restrict__ x,
                                                const float* __restrict__ msc,
                                                const int* __restrict__ cls,
                                                float* __restrict__ out) {
#pragma clang fp contract(off)
    __shared__ __align__(16) unsigned char uni[CAP * 8];  // keys | bm+sup
    __shared__ unsigned hh[NBINS];       // pass-A counts (persist for rank)
    __shared__ unsigned hbase[NBINS];    // suffix bases -> scatter cursors
    __shared__ __align__(16) float4 obx[NTOP];   // un-offset xyxy
    __shared__ float oco[NTOP];                  // cls * 4096
    __shared__ float osc[NTOP];                  // score
    __shared__ int   ocl[NTOP];                  // class id, -1 if invalid
    __shared__ int sB;
    __shared__ int ovf;
    u64* keys = (u64*)uni;
    const int b = blockIdx.x, t = threadIdx.x;
    const float4* ms4 = (const float4*)(msc + (size_t)b * NPRED);  // 16B-aligned

    // single global pass, vectorized: 7 float4 regs/thread (7*4*1024 >= 25200)
    float4 sv4[7];
#pragma unroll
    for (int k = 0; k < 7; ++k) {
        int f4i = t + k * 1024;
        sv4[k] = (f4i < NPRED / 4) ? ms4[f4i]
                                   : make_float4(-1.f, -1.f, -1.f, -1.f);
    }

    for (int i = t; i < NBINS; i += 1024) hh[i] = 0;
    keys[t] = ~0ULL; keys[t + 1024] = ~0ULL;
    if (t < NTOP) ocl[t] = -1;
    if (t == 0) { ovf = 0; sB = 0; }
    __syncthreads();

    // pass A: per-batch histogram of score bits (LDS atomics, from regs)
#pragma unroll
    for (int k = 0; k < 7; ++k) {
        const float* f = (const float*)&sv4[k];
#pragma unroll
        for (int j = 0; j < 4; ++j) {
            float s = f[j];
            if (s > CONF_T) {
                unsigned bits = __float_as_uint(s);
                int bin = (int)(bits >> 14) - 0xFA00;
                bin = bin < 0 ? 0 : (bin > 1024 ? 1024 : bin);
                atomicAdd(&hh[bin], 1u);
            }
        }
    }
    __syncthreads();

    if (t < 64) {  // wave 0: suffix bases for ALL bins + boundary bin B
        const int lane = t;
        const int hi2 = 1024 - 16 * lane;       // lane chunk: bins [hi2-15, hi2]
        unsigned lc[16];
        unsigned sum = 0;
#pragma unroll
        for (int k = 0; k < 16; ++k) { lc[k] = hh[hi2 - k]; sum += lc[k]; }
        if (lane == 63) sum += hh[0];
        unsigned v = sum;
        for (int d = 1; d < 64; d <<= 1) {
            unsigned o = __shfl_up(v, d);
            if (lane >= d) v += o;
        }
        unsigned excl = v - sum;                // count strictly above my chunk
        // per-bin rank bases: hbase[bin] = #candidates in bins > bin
        unsigned run = excl;
#pragma unroll
        for (int k = 0; k < 16; ++k) { hbase[hi2 - k] = run; run += lc[k]; }
        if (lane == 63) hbase[0] = run;         // bin 0 (run excludes hh[0])
        // boundary bin B
        u64 ball = __ballot(v >= NTOP);
        int B = 0;
        if (ball != 0) {
            int sel = __builtin_ctzll(ball);
            if (lane == sel) {
                unsigned r2 = excl;
                for (int k = 0; k < 16; ++k) {
                    r2 += lc[k];
                    if (r2 >= NTOP) { B = hi2 - k; break; }
                }
            }
            B = __shfl(B, sel);
        }
        if (lane == 0) sB = B;
    }
    __syncthreads();
    const int B = sB;

    // pass B: scatter candidates (bin >= B) to their bin segment (from regs)
#pragma unroll
    for (int k = 0; k < 7; ++k) {
        const float* f = (const float*)&sv4[k];
#pragma unroll
        for (int j = 0; j < 4; ++j) {
            float s = f[j];
            if (s > CONF_T) {
                unsigned bits = __float_as_uint(s);
                int bin = (int)(bits >> 14) - 0xFA00;
                bin = bin < 0 ? 0 : (bin > 1024 ? 1024 : bin);
                if (bin >= B) {
                    unsigned slot = atomicAdd(&hbase[bin], 1u);
                    if (slot < (unsigned)CAP)
                        keys[slot] = ((u64)(~bits) << 32)
                                   | (unsigned)((t + k * 1024) * 4 + j);
                }
            }
        }
    }
    __syncthreads();

    // fused rank + gather: exact rank = base + #{same-bin keys < mine};
    // the x-row loads are issued BEFORE the count loop (address is rank-
    // independent) so their latency hides under the LDS counting.
    {
        auto binOf = [](u64 kk) -> int {
            unsigned bits = ~(unsigned)(kk >> 32);
            int bin = (int)(bits >> 14) - 0xFA00;
            return bin < 0 ? 0 : (bin > 1024 ? 1024 : bin);
        };
#pragma unroll
        for (int pp = 0; pp < 2; ++pp) {
            int i = t + pp * 1024;
            u64 my = keys[i];
            if (my == ~0ULL) continue;
            // issue gather loads first (independent of rank)
            unsigned p = (unsigned)my;
            const float* xp = x + ((size_t)b * NPRED + p) * 85;
            float xc = xp[0], yc = xp[1], w = xp[2], h = xp[3];
            int cid = cls[(size_t)b * NPRED + p];
            // rank count (LDS, ~25-wide segment, no dependent chain)
            int bin = binOf(my);
            int e2 = (int)hbase[bin];           // base + n (post-scatter cursor)
            if (e2 > CAP) e2 = CAP;
            int base = e2 - (int)hh[bin];
            if (base < 0) base = 0;
            unsigned r = (unsigned)base;
            for (int j = base; j < e2; ++j) r += (keys[j] < my) ? 1u : 0u;
            if (r < (unsigned)NTOP) {
                float hw = w * 0.5f, hh2 = h * 0.5f;
                obx[r] = make_float4(xc - hw, yc - hh2, xc + hw, yc + hh2);
                oco[r] = (float)cid * MAXWH;
                osc[r] = __uint_as_float(~(unsigned)(my >> 32));
                ocl[r] = cid;
            }
        }
    }
    __syncthreads();    // keys dead; overlay per-class rank bitmasks + sup

    u64* bm = (u64*)uni;                  // [80][16] u64 = 10240 B
    unsigned char* sup = uni + 10240;     // 1000 B
    for (int i = t; i < NCLS * 16; i += 1024) bm[i] = 0;
    if (t < NTOP) sup[t] = 0;
    __syncthreads();
    if (t < NTOP && ocl[t] >= 0)
        atomicOr(&bm[ocl[t] * 16 + (t >> 6)], 1ull << (t & 63));
    __syncthreads();

    // ---- per-class ballot greedy: one wave per class, lane = rank order ----
    {
        const int wave = t >> 6, lane = t & 63;
        for (int c2 = wave; c2 < NCLS; c2 += 16) {
            u64 w = (lane < 16) ? bm[c2 * 16 + lane] : 0ull;
            int cum = 0, myw = -1, rem = 0;
            u64 myword = 0;
#pragma unroll
            for (int ww = 0; ww < 16; ++ww) {
                u64 wv = shfl_u64(w, ww);
                int pc = __popcll(wv);
                if (myw < 0 && lane < cum + pc) { myw = ww; rem = lane - cum; myword = wv; }
                cum += pc;
            }
            int n2 = cum;
            if (n2 == 0) continue;
            if (n2 > 64) { ovf = 1; continue; }   // benign race (all write 1)
            bool active = (lane < n2);
            int rank = 0;
            float ax1v = 0.f, ay1v = 0.f, ax2v = 0.f, ay2v = 0.f, arv = 0.f;
            if (active) {
                int pos = 0, r = rem;   // select rem-th set bit of myword
#pragma unroll
                for (int wd = 32; wd >= 1; wd >>= 1) {
                    u64 mask = ((1ull << wd) - 1ull) << pos;
                    int cc = __popcll(myword & mask);
                    if (r >= cc) { r -= cc; pos += wd; }
                }
                rank = myw * 64 + pos;
                float4 A = obx[rank]; float cA = oco[rank];
                ax1v = A.x + cA; ay1v = A.y + cA;
                ax2v = A.z + cA; ay2v = A.w + cA;
                arv = (ax2v - ax1v) * (ay2v - ay1v);
            }
            u64 alive = (n2 >= 64) ? ~0ull : ((1ull << n2) - 1ull);
            u64 kept = 0;
            while (alive) {
                int i = (int)__builtin_ctzll(alive);
                u64 bit = 1ull << i;
                kept |= bit;
                float bx1 = __shfl(ax1v, i), by1 = __shfl(ay1v, i);
                float bx2 = __shfl(ax2v, i), by2 = __shfl(ay2v, i);
                float bar = __shfl(arv, i);
                float ltx = fmaxf(bx1, ax1v), lty = fmaxf(by1, ay1v);
                float rbx = fminf(bx2, ax2v), rby = fminf(by2, ay2v);
                float ww2 = fmaxf(rbx - ltx, 0.0f), hh3 = fmaxf(rby - lty, 0.0f);
                float inter = ww2 * hh3;
                float iou = inter / (((bar + arv) - inter) + 1e-9f);
                u64 suppr = __ballot(iou > IOU_THR);
                alive &= ~(suppr | bit);
            }
            if (active) sup[rank] = ((kept >> lane) & 1ull) ? 0 : 1;
        }
    }
    __syncthreads();

    // exact serial fallback for classes with >64 candidates (P ~ 1e-40)
    if (ovf && t == 0) {
        for (int c2 = 0; c2 < NCLS; ++c2) {
            int n2 = 0;
            for (int w2 = 0; w2 < 16; ++w2) n2 += __popcll(bm[c2 * 16 + w2]);
            if (n2 <= 64) continue;
            for (int a2 = 0; a2 < NTOP; ++a2) {
                if (ocl[a2] != c2 || sup[a2]) continue;
                float4 A = obx[a2]; float cA = oco[a2];
                float ax1 = A.x + cA, ay1 = A.y + cA;
                float ax2 = A.z + cA, ay2 = A.w + cA;
                float areaA = (ax2 - ax1) * (ay2 - ay1);
                for (int d2 = a2 + 1; d2 < NTOP; ++d2) {
                    if (ocl[d2] != c2 || sup[d2]) continue;
                    float4 Bb = obx[d2];
                    float bx1 = Bb.x + cA, by1 = Bb.y + cA;
                    float bx2 = Bb.z + cA, by2 = Bb.w + cA;
                    float ltx = fmaxf(ax1, bx1), lty = fmaxf(ay1, by1);
                    float rbx = fminf(ax2, bx2), rby = fminf(ay2, by2);
                    float ww = fmaxf(rbx - ltx, 0.0f), hh3 = fmaxf(rby - lty, 0.0f);
                    float inter = ww * hh3;
                    float areaB = (bx2 - bx1) * (by2 - by1);
                    float iou = inter / (((areaA + areaB) - inter) + 1e-9f);
                    if (iou > IOU_THR) sup[d2] = 1;
                }
            }
        }
    }
    __syncthreads();

    // masked output write
    if (t < NTOP) {
        bool keep = (ocl[t] >= 0) && (sup[t] == 0);
        float4 o = obx[t];
        size_t d6 = ((size_t)b * NTOP + t) * 6;
        out[d6 + 0] = keep ? o.x : 0.0f;
        out[d6 + 1] = keep ? o.y : 0.0f;
        out[d6 + 2] = keep ? o.z : 0.0f;
        out[d6 + 3] = keep ? o.w : 0.0f;
        out[d6 + 4] = keep ? osc[t] : 0.0f;
        out[d6 + 5] = keep ? (float)ocl[t] : 0.0f;
    }
}

// ---------------------------------------------------------------------------
extern "C" void kernel_launch(void* const* d_in, const int* in_sizes, int n_in,
                              void* d_out, int out_size, void* d_ws, size_t ws_size,
                              hipStream_t stream) {
    const float* x = (const float*)d_in[0];
    char* ws = (char*)d_ws;
    float* msc = (float*)(ws);                       //      0 .. 806400
    int* cls = (int*)(ws + 806400);                  // 806400 .. 1612800

    k_score<<<NB * SBPB, 256, 0, stream>>>(x, msc, cls);
    k_fused<<<NB, 1024, 0, stream>>>(x, msc, cls, (float*)d_out);
}